// Round 6
// baseline (74.928 us; speedup 1.0000x reference)
//
#include <hip/hip_runtime.h>
#include <stdint.h>

#define ROWS 8192     // B*N
#define D    128
#define NSB  32       // 256-row strips
#define BN   64
#define NSLOT 64      // row-sum slots 2J+h, col-sum slots I (per-row disjoint)
#define SQRT_LOG2E 1.2011224087864498f

typedef __bf16 bf16x8 __attribute__((ext_vector_type(8)));
typedef float  f32x4  __attribute__((ext_vector_type(4)));

typedef const __attribute__((address_space(1))) uint32_t guint;
typedef __attribute__((address_space(3))) uint32_t luint;

__device__ __forceinline__ void gload_lds16(const void* g, void* l) {
    __builtin_amdgcn_global_load_lds((guint*)g, (luint*)l, 16, 0, 0);
}

__device__ __forceinline__ ushort f2bf(float f) {
    union { float f; uint32_t u; } x; x.f = f;
    uint32_t r = x.u + 0x7FFFu + ((x.u >> 16) & 1u);
    return (ushort)(r >> 16);
}

// ---- Kernel 1: L2-normalize rows, cast to bf16; fk scaled by sqrt(log2e)
// so exp(logit) == exp2(Gk). ----
__global__ __launch_bounds__(256) void k_norm(
    const float* __restrict__ fk, const float* __restrict__ fq,
    ushort* __restrict__ fkn, ushort* __restrict__ fqn)
{
    int gw = (blockIdx.x * 256 + threadIdx.x) >> 6;   // one wave per row
    int l  = threadIdx.x & 63;
    const float* src; ushort* dst; int r; float scale;
    if (gw < ROWS) { src = fk; dst = fkn; r = gw; scale = SQRT_LOG2E; }
    else           { src = fq; dst = fqn; r = gw - ROWS; scale = 1.0f; }
    float2 v = *reinterpret_cast<const float2*>(&src[r * D + l * 2]);
    float ss = v.x * v.x + v.y * v.y;
    #pragma unroll
    for (int m = 1; m < 64; m <<= 1) ss += __shfl_xor(ss, m, 64);
    float inv = scale / fmaxf(sqrtf(ss), 1e-12f);
    ushort2 o; o.x = f2bf(v.x * inv); o.y = f2bf(v.y * inv);
    *reinterpret_cast<ushort2*>(&dst[r * D + l * 2]) = o;
}

// ---- Kernel 2: symmetric fused Gram, balanced 512-block partition.
// Strip I (rows [256I,256I+256)) owns col-tiles [4I, 128) (BN=64 each).
// Strip tiles are partitioned into contiguous blocks of 4 or 5 tiles:
// strips I<16: 4 five-tile blocks then fours; strips I>=16: all fours.
// Total = sum_{I<16}(31-I) + sum_{I>=16}(32-I) = 376 + 136 = 512 blocks,
// all resident in ONE round (2 blocks/CU, LDS-capped). ----
__global__ __launch_bounds__(512, 4) void k_gram(
    const ushort* __restrict__ fkn, const ushort* __restrict__ fqn,
    float* __restrict__ pneg, float* __restrict__ ppos)
{
    __shared__ ushort lds[2][2 * BN * D];   // 2 bufs x (fk 16KB + fq 16KB) = 64 KiB
    // ---- decode block -> (strip I, tile range) ----
    int b = blockIdx.x;
    int I = 0;
    #pragma unroll 1
    for (; I < 31; ++I) {
        int nI = (I < 16) ? (31 - I) : (32 - I);
        if (b < nI) break;
        b -= nI;
    }
    const int k = b;
    const int nt = (I < 16 && k < 4) ? 5 : 4;
    const int tstart = (I < 16) ? (k < 4 ? k * 5 : 20 + (k - 4) * 4) : k * 4;
    const int ct0 = I * 4 + tstart;          // first global col-tile
    const int r0 = I * 256;

    const int w = threadIdx.x >> 6;          // 0..7
    const int l = threadIdx.x & 63;
    const int lrow = l >> 4, lcol = l & 15;

    // Pre-swizzled global source offsets (rule #21).
    int off[2];
    #pragma unroll
    for (int i = 0; i < 2; ++i) {
        int L = w * 128 + i * 64 + l;
        int row = L >> 4, slot = L & 15;
        off[i] = row * 256 + (slot ^ (row & 7)) * 16;
    }

    auto issue_stage = [&](int buf, int cbase) {
        const char* fkb = (const char*)fkn + (size_t)cbase * 256;
        const char* fqb = (const char*)fqn + (size_t)cbase * 256;
        ushort* lk = &lds[buf][w * 1024];
        ushort* lq = &lds[buf][BN * D + w * 1024];
        gload_lds16(fkb + off[0], lk);
        gload_lds16(fkb + off[1], lk + 512);
        gload_lds16(fqb + off[0], lq);
        gload_lds16(fqb + off[1], lq + 512);
    };

    issue_stage(0, ct0 * 64);

    // A fragments (2 row-groups x 4 k-steps, both tensors), global->reg once.
    bf16x8 ak[2][4], aq[2][4];
    #pragma unroll
    for (int rg = 0; rg < 2; ++rg) {
        int arow = r0 + w * 32 + rg * 16 + lcol;      // A row: m = lane&15
        #pragma unroll
        for (int ks = 0; ks < 4; ++ks) {              // k = ks*32 + (lane>>4)*8 + e
            ak[rg][ks] = *reinterpret_cast<const bf16x8*>(fkn + arow * D + ks * 32 + lrow * 8);
            aq[rg][ks] = *reinterpret_cast<const bf16x8*>(fqn + arow * D + ks * 32 + lrow * 8);
        }
    }

    const int diagct = (r0 + w * 32) >> 6;   // wave's own 64-block col-tile
    const bool haspos = (tstart == 0);       // k=0 block covers tiles 0..3 => all diag tiles

    float accn[2][4] = {};      // row-sums for current supertile J
    float colacc[5][4] = {};    // per-lane col partials, [local tile][cc]
    float posacc[2][4] = {};

    __syncthreads();

    #pragma unroll
    for (int t = 0; t < 5; ++t) {
        if (t < nt) {
            const int cur = t & 1;
            if (t + 1 < nt) issue_stage(cur ^ 1, (ct0 + t + 1) * 64);   // async prefetch
            const int ct = ct0 + t;
            const bool dtile  = (ct == diagct);         // wave-uniform
            const bool indiag = (ct < 4 * I + 4);       // inside (I,I) supertile
            const ushort* bkb = &lds[cur][0];
            const ushort* bqb = &lds[cur][BN * D];
            #pragma unroll
            for (int cc = 0; cc < 4; ++cc) {
                int brow = cc * 16 + lcol;              // B row: n = lane&15
                bf16x8 bk[4], bq[4];
                #pragma unroll
                for (int ks = 0; ks < 4; ++ks) {
                    int slot = (ks * 4 + lrow) ^ (brow & 7);
                    bk[ks] = *reinterpret_cast<const bf16x8*>(bkb + brow * 128 + slot * 8);
                    bq[ks] = *reinterpret_cast<const bf16x8*>(bqb + brow * 128 + slot * 8);
                }
                f32x4 sk0 = {0,0,0,0}, sk1 = {0,0,0,0}, sq0 = {0,0,0,0}, sq1 = {0,0,0,0};
                __builtin_amdgcn_s_setprio(1);
                #pragma unroll
                for (int ks = 0; ks < 4; ++ks) {
                    sk0 = __builtin_amdgcn_mfma_f32_16x16x32_bf16(ak[0][ks], bk[ks], sk0, 0, 0, 0);
                    sk1 = __builtin_amdgcn_mfma_f32_16x16x32_bf16(ak[1][ks], bk[ks], sk1, 0, 0, 0);
                    sq0 = __builtin_amdgcn_mfma_f32_16x16x32_bf16(aq[0][ks], bq[ks], sq0, 0, 0, 0);
                    sq1 = __builtin_amdgcn_mfma_f32_16x16x32_bf16(aq[1][ks], bq[ks], sq1, 0, 0, 0);
                }
                __builtin_amdgcn_s_setprio(0);
                // C layout: row = (lane>>4)*4 + e, col = lane&15
                if (dtile) {
                    #pragma unroll
                    for (int e = 0; e < 4; ++e) {
                        posacc[0][e] += __builtin_exp2f(sk0[e]);
                        posacc[1][e] += __builtin_exp2f(sk1[e]);
                    }
                } else {
                    float psum = 0.f;
                    #pragma unroll
                    for (int e = 0; e < 4; ++e) {
                        float p0 = __builtin_exp2f(sk0[e]) * sq0[e];
                        float p1 = __builtin_exp2f(sk1[e]) * sq1[e];
                        accn[0][e] += p0;
                        accn[1][e] += p1;
                        psum += p0 + p1;
                    }
                    if (!indiag) colacc[t][cc] += psum;       // block-uniform guard
                }
            }
            // ---- flush row-sums when this supertile J ends ----
            const int J = ct >> 2;
            if (t == nt - 1 || ((ct + 1) >> 2) != J) {
                #pragma unroll
                for (int m = 1; m <= 8; m <<= 1)
                    #pragma unroll
                    for (int rg = 0; rg < 2; ++rg)
                        #pragma unroll
                        for (int e = 0; e < 4; ++e)
                            accn[rg][e] += __shfl_xor(accn[rg][e], m, 64);
                const int h = (ct0 <= 4 * J) ? 0 : 1;   // block containing tile 4J -> 0
                if (lcol == 0) {
                    #pragma unroll
                    for (int rg = 0; rg < 2; ++rg)
                        #pragma unroll
                        for (int e = 0; e < 4; ++e) {
                            int gr = r0 + w * 32 + rg * 16 + lrow * 4 + e;
                            pneg[(2 * J + h) * ROWS + gr] = accn[rg][e];
                        }
                    }
                #pragma unroll
                for (int rg = 0; rg < 2; ++rg)
                    #pragma unroll
                    for (int e = 0; e < 4; ++e) accn[rg][e] = 0.f;
            }
            __syncthreads();
        }
    }

    // ---- pos write (only strip's k=0 block; every wave hit its dtile) ----
    #pragma unroll
    for (int m = 1; m <= 8; m <<= 1)
        #pragma unroll
        for (int rg = 0; rg < 2; ++rg)
            #pragma unroll
            for (int e = 0; e < 4; ++e)
                posacc[rg][e] += __shfl_xor(posacc[rg][e], m, 64);
    if (haspos && lcol == 0) {
        #pragma unroll
        for (int rg = 0; rg < 2; ++rg)
            #pragma unroll
            for (int e = 0; e < 4; ++e) {
                int gr = r0 + w * 32 + rg * 16 + lrow * 4 + e;
                ppos[gr] = posacc[rg][e];
            }
    }

    // ---- col-sum epilogue: slot I, one unique writer per column ----
    #pragma unroll
    for (int i = 0; i < 5; ++i)
        #pragma unroll
        for (int cc = 0; cc < 4; ++cc) {
            colacc[i][cc] += __shfl_xor(colacc[i][cc], 16, 64);
            colacc[i][cc] += __shfl_xor(colacc[i][cc], 32, 64);
        }
    float* colbuf = (float*)&lds[0][0];   // 8 waves x 320 cols x 4B = 10 KB
    if (l < 16) {
        #pragma unroll
        for (int i = 0; i < 5; ++i)
            #pragma unroll
            for (int cc = 0; cc < 4; ++cc)
                colbuf[w * 320 + i * 64 + cc * 16 + l] = colacc[i][cc];  // 0 for indiag tiles
    }
    __syncthreads();
    {
        int cl = threadIdx.x;
        if (cl < nt * 64) {
            int ct = ct0 + (cl >> 6);
            if (ct >= 4 * I + 4) {                 // skip (I,I): handled by row-sums
                float s = 0.f;
                #pragma unroll
                for (int ww = 0; ww < 8; ++ww) s += colbuf[ww * 320 + cl];
                pneg[I * ROWS + ct * 64 + (cl & 63)] = s;
            }
        }
    }
}

// ---- Kernel 3a: per-row loss, 32-block partial sums ----
__global__ __launch_bounds__(256) void k_loss1(
    const float* __restrict__ pneg, const float* __restrict__ ppos,
    float* __restrict__ bsum)
{
    int r = blockIdx.x * 256 + threadIdx.x;
    float pos = ppos[r];
    float neg = 0.f;
    #pragma unroll
    for (int p = 0; p < NSLOT; ++p) neg += pneg[p * ROWS + r];
    float s = log1pf(neg / pos);
    #pragma unroll
    for (int m = 1; m < 64; m <<= 1) s += __shfl_xor(s, m, 64);
    __shared__ float red[4];
    if ((threadIdx.x & 63) == 0) red[threadIdx.x >> 6] = s;
    __syncthreads();
    if (threadIdx.x == 0) bsum[blockIdx.x] = red[0] + red[1] + red[2] + red[3];
}

// ---- Kernel 3b: final mean ----
__global__ void k_loss2(const float* __restrict__ bsum, float* __restrict__ out)
{
    int l = threadIdx.x;
    float s = (l < 32) ? bsum[l] : 0.f;
    #pragma unroll
    for (int m = 1; m < 64; m <<= 1) s += __shfl_xor(s, m, 64);
    if (l == 0) out[0] = s * (1.0f / ROWS);
}

extern "C" void kernel_launch(void* const* d_in, const int* in_sizes, int n_in,
                              void* d_out, int out_size, void* d_ws, size_t ws_size,
                              hipStream_t stream)
{
    const float* fk = (const float*)d_in[0];
    const float* fq = (const float*)d_in[1];
    ushort* fkn = (ushort*)d_ws;                        // 2 MB
    ushort* fqn = fkn + ROWS * D;                       // 2 MB
    float*  pneg = (float*)(fqn + ROWS * D);            // 64*8192*4 = 2 MB
    float*  ppos = pneg + NSLOT * ROWS;                 // 32 KB
    float*  bsum = ppos + ROWS;                         // 128 B

    hipMemsetAsync(pneg, 0, (size_t)NSLOT * ROWS * sizeof(float), stream);
    k_norm<<<(2 * ROWS) / 4, 256, 0, stream>>>(fk, fq, fkn, fqn);
    k_gram<<<512, 512, 0, stream>>>(fkn, fqn, pneg, ppos);
    k_loss1<<<32, 256, 0, stream>>>(pneg, ppos, bsum);
    k_loss2<<<1, 64, 0, stream>>>(bsum, (float*)d_out);
}

// Round 7
// 62.622 us; speedup vs baseline: 1.1965x; 1.1965x over previous
//
#include <hip/hip_runtime.h>
#include <stdint.h>

#define ROWS 8192     // B*N
#define D    128
#define NSB  32       // 256-row/col super-blocks
#define BN   64
#define NBLK (NSB * (NSB + 1) / 2)   // 528 = 8 * 66
#define SQRT_LOG2E 1.2011224087864498f

typedef __bf16 bf16x8 __attribute__((ext_vector_type(8)));
typedef float  f32x4  __attribute__((ext_vector_type(4)));

typedef const __attribute__((address_space(1))) uint32_t guint;
typedef __attribute__((address_space(3))) uint32_t luint;

__device__ __forceinline__ void gload_lds16(const void* g, void* l) {
    __builtin_amdgcn_global_load_lds((guint*)g, (luint*)l, 16, 0, 0);
}

__device__ __forceinline__ ushort f2bf(float f) {
    union { float f; uint32_t u; } x; x.f = f;
    uint32_t r = x.u + 0x7FFFu + ((x.u >> 16) & 1u);
    return (ushort)(r >> 16);
}

// ---- Kernel 1: L2-normalize rows, cast to bf16; fk scaled by sqrt(log2e)
// so exp(logit) == exp2(Gk). ----
__global__ __launch_bounds__(256) void k_norm(
    const float* __restrict__ fk, const float* __restrict__ fq,
    ushort* __restrict__ fkn, ushort* __restrict__ fqn)
{
    int gw = (blockIdx.x * 256 + threadIdx.x) >> 6;   // one wave per row
    int l  = threadIdx.x & 63;
    const float* src; ushort* dst; int r; float scale;
    if (gw < ROWS) { src = fk; dst = fkn; r = gw; scale = SQRT_LOG2E; }
    else           { src = fq; dst = fqn; r = gw - ROWS; scale = 1.0f; }
    float2 v = *reinterpret_cast<const float2*>(&src[r * D + l * 2]);
    float ss = v.x * v.x + v.y * v.y;
    #pragma unroll
    for (int m = 1; m < 64; m <<= 1) ss += __shfl_xor(ss, m, 64);
    float inv = scale / fmaxf(sqrtf(ss), 1e-12f);
    ushort2 o; o.x = f2bf(v.x * inv); o.y = f2bf(v.y * inv);
    *reinterpret_cast<ushort2*>(&dst[r * D + l * 2]) = o;
}

// ---- Kernel 2: symmetric fused Gram, COLUMN-MAJOR supertile order.
// One block per upper-tri 256x256 supertile (I,J), I<=J. Enumeration is
// J-descending with I inner, so consecutive blocks share supertile-column J
// (identical B col-stream => R2-grade L2 sharing). XCD chunk swizzle
// (528 = 8*66, bijective) keeps each XCD on a contiguous J range.
// Row r of strip I gets slot J from (I,J) row-sums (J>=I, incl diag) and
// slot I' from (I',I) col-sums (I'<I): all 32 slots written exactly once.
__global__ __launch_bounds__(512, 4) void k_gram(
    const ushort* __restrict__ fkn, const ushort* __restrict__ fqn,
    float* __restrict__ pneg, float* __restrict__ ppos)
{
    __shared__ ushort lds[2][2 * BN * D];   // 2 bufs x (fk 16KB + fq 16KB) = 64 KiB
    // ---- decode block -> (I, J) ----
    const int b  = blockIdx.x;
    const int ws = (b & 7) * (NBLK / 8) + (b >> 3);   // XCD chunk swizzle
    const int q  = (NBLK - 1) - ws;                   // ascending tri index: J asc
    int J = (int)((sqrtf(8.0f * (float)q + 1.0f) - 1.0f) * 0.5f);
    while ((J + 1) * (J + 2) / 2 <= q) ++J;
    while (J * (J + 1) / 2 > q) --J;
    const int I = q - J * (J + 1) / 2;
    const bool isdiag = (I == J);
    const int r0 = I * 256;
    const int c0 = J * 256;

    const int w = threadIdx.x >> 6;          // 0..7
    const int l = threadIdx.x & 63;
    const int lrow = l >> 4, lcol = l & 15;

    // Pre-swizzled global source offsets (rule #21): gload_lds writes LDS
    // linearly; chunk L -> row=L>>4, slot=L&15, src col = slot^(row&7).
    int off[2];
    #pragma unroll
    for (int i = 0; i < 2; ++i) {
        int L = w * 128 + i * 64 + l;
        int row = L >> 4, slot = L & 15;
        off[i] = row * 256 + (slot ^ (row & 7)) * 16;
    }

    auto issue_stage = [&](int buf, int cbase) {
        const char* fkb = (const char*)fkn + (size_t)cbase * 256;
        const char* fqb = (const char*)fqn + (size_t)cbase * 256;
        ushort* lk = &lds[buf][w * 1024];
        ushort* lq = &lds[buf][BN * D + w * 1024];
        gload_lds16(fkb + off[0], lk);
        gload_lds16(fkb + off[1], lk + 512);
        gload_lds16(fqb + off[0], lq);
        gload_lds16(fqb + off[1], lq + 512);
    };

    issue_stage(0, c0);

    // A fragments (2 row-groups x 4 k-steps, both tensors), global->reg once.
    bf16x8 ak[2][4], aq[2][4];
    #pragma unroll
    for (int rg = 0; rg < 2; ++rg) {
        int arow = r0 + w * 32 + rg * 16 + lcol;      // A row: m = lane&15
        #pragma unroll
        for (int ks = 0; ks < 4; ++ks) {              // k = ks*32 + (lane>>4)*8 + e
            ak[rg][ks] = *reinterpret_cast<const bf16x8*>(fkn + arow * D + ks * 32 + lrow * 8);
            aq[rg][ks] = *reinterpret_cast<const bf16x8*>(fqn + arow * D + ks * 32 + lrow * 8);
        }
    }

    const int diagct = (r0 + w * 32) >> 6;   // wave's own 64-col-tile index
    float accn[2][4]   = {};                 // row-sums -> slot J
    float colacc[4][4] = {};                 // col partials, [tile][cc] -> slot I
    float posacc[2][4] = {};                 // diag supertile only

    __syncthreads();

    #pragma unroll
    for (int t = 0; t < 4; ++t) {
        const int cur = t & 1;
        if (t + 1 < 4) issue_stage(cur ^ 1, c0 + (t + 1) * BN);   // async prefetch
        const int ct = 4 * J + t;
        const bool dtile = isdiag && (ct == diagct);              // wave-uniform
        const ushort* bkb = &lds[cur][0];
        const ushort* bqb = &lds[cur][BN * D];
        #pragma unroll
        for (int cc = 0; cc < 4; ++cc) {
            int brow = cc * 16 + lcol;                            // B row: n = lane&15
            bf16x8 bk[4], bq[4];
            #pragma unroll
            for (int ks = 0; ks < 4; ++ks) {
                int slot = (ks * 4 + lrow) ^ (brow & 7);
                bk[ks] = *reinterpret_cast<const bf16x8*>(bkb + brow * 128 + slot * 8);
                bq[ks] = *reinterpret_cast<const bf16x8*>(bqb + brow * 128 + slot * 8);
            }
            f32x4 sk0 = {0,0,0,0}, sk1 = {0,0,0,0}, sq0 = {0,0,0,0}, sq1 = {0,0,0,0};
            __builtin_amdgcn_s_setprio(1);
            #pragma unroll
            for (int ks = 0; ks < 4; ++ks) {
                sk0 = __builtin_amdgcn_mfma_f32_16x16x32_bf16(ak[0][ks], bk[ks], sk0, 0, 0, 0);
                sk1 = __builtin_amdgcn_mfma_f32_16x16x32_bf16(ak[1][ks], bk[ks], sk1, 0, 0, 0);
                sq0 = __builtin_amdgcn_mfma_f32_16x16x32_bf16(aq[0][ks], bq[ks], sq0, 0, 0, 0);
                sq1 = __builtin_amdgcn_mfma_f32_16x16x32_bf16(aq[1][ks], bq[ks], sq1, 0, 0, 0);
            }
            __builtin_amdgcn_s_setprio(0);
            // C layout: row = (lane>>4)*4 + e, col = lane&15
            if (dtile) {
                #pragma unroll
                for (int e = 0; e < 4; ++e) {
                    posacc[0][e] += __builtin_exp2f(sk0[e]);
                    posacc[1][e] += __builtin_exp2f(sk1[e]);
                }
            } else {
                float psum = 0.f;
                #pragma unroll
                for (int e = 0; e < 4; ++e) {
                    float p0 = __builtin_exp2f(sk0[e]) * sq0[e];
                    float p1 = __builtin_exp2f(sk1[e]) * sq1[e];
                    accn[0][e] += p0;
                    accn[1][e] += p1;
                    psum += p0 + p1;
                }
                if (!isdiag) colacc[t][cc] += psum;       // block-uniform guard
            }
        }
        __syncthreads();   // next tile staged (vmcnt) + reads of cur done (lgkm)
    }

    // ---- row-sum flush: slot J for rows of strip I ----
    #pragma unroll
    for (int m = 1; m <= 8; m <<= 1)
        #pragma unroll
        for (int rg = 0; rg < 2; ++rg)
            #pragma unroll
            for (int e = 0; e < 4; ++e) {
                accn[rg][e]   += __shfl_xor(accn[rg][e], m, 64);
                posacc[rg][e] += __shfl_xor(posacc[rg][e], m, 64);
            }
    if (lcol == 0) {
        #pragma unroll
        for (int rg = 0; rg < 2; ++rg)
            #pragma unroll
            for (int e = 0; e < 4; ++e) {
                int gr = r0 + w * 32 + rg * 16 + lrow * 4 + e;
                pneg[J * ROWS + gr] = accn[rg][e];
                if (isdiag) ppos[gr] = posacc[rg][e];
            }
    }

    // ---- col-sum epilogue (off-diag only): slot I for rows of strip J ----
    if (!isdiag) {
        #pragma unroll
        for (int t = 0; t < 4; ++t)
            #pragma unroll
            for (int cc = 0; cc < 4; ++cc) {
                colacc[t][cc] += __shfl_xor(colacc[t][cc], 16, 64);
                colacc[t][cc] += __shfl_xor(colacc[t][cc], 32, 64);
            }
        float* colbuf = (float*)&lds[0][0];   // 8 waves x 256 cols x 4B = 8 KB
        if (l < 16) {
            #pragma unroll
            for (int t = 0; t < 4; ++t)
                #pragma unroll
                for (int cc = 0; cc < 4; ++cc)
                    colbuf[w * 256 + t * 64 + cc * 16 + l] = colacc[t][cc];
        }
        __syncthreads();
        if (threadIdx.x < 256) {
            int c = threadIdx.x;
            float s = 0.f;
            #pragma unroll
            for (int ww = 0; ww < 8; ++ww) s += colbuf[ww * 256 + c];
            pneg[I * ROWS + c0 + c] = s;
        }
    }
}

// ---- Kernel 3a: per-row loss, 32-block partial sums ----
__global__ __launch_bounds__(256) void k_loss1(
    const float* __restrict__ pneg, const float* __restrict__ ppos,
    float* __restrict__ bsum)
{
    int r = blockIdx.x * 256 + threadIdx.x;
    float pos = ppos[r];
    float neg = 0.f;
    #pragma unroll
    for (int p = 0; p < NSB; ++p) neg += pneg[p * ROWS + r];
    float s = log1pf(neg / pos);
    #pragma unroll
    for (int m = 1; m < 64; m <<= 1) s += __shfl_xor(s, m, 64);
    __shared__ float red[4];
    if ((threadIdx.x & 63) == 0) red[threadIdx.x >> 6] = s;
    __syncthreads();
    if (threadIdx.x == 0) bsum[blockIdx.x] = red[0] + red[1] + red[2] + red[3];
}

// ---- Kernel 3b: final mean ----
__global__ void k_loss2(const float* __restrict__ bsum, float* __restrict__ out)
{
    int l = threadIdx.x;
    float s = (l < 32) ? bsum[l] : 0.f;
    #pragma unroll
    for (int m = 1; m < 64; m <<= 1) s += __shfl_xor(s, m, 64);
    if (l == 0) out[0] = s * (1.0f / ROWS);
}

extern "C" void kernel_launch(void* const* d_in, const int* in_sizes, int n_in,
                              void* d_out, int out_size, void* d_ws, size_t ws_size,
                              hipStream_t stream)
{
    const float* fk = (const float*)d_in[0];
    const float* fq = (const float*)d_in[1];
    ushort* fkn = (ushort*)d_ws;                        // 2 MB
    ushort* fqn = fkn + ROWS * D;                       // 2 MB
    float*  pneg = (float*)(fqn + ROWS * D);            // 32*8192*4 = 1 MB
    float*  ppos = pneg + NSB * ROWS;                   // 32 KB
    float*  bsum = ppos + ROWS;                         // 128 B

    k_norm<<<(2 * ROWS) / 4, 256, 0, stream>>>(fk, fq, fkn, fqn);
    k_gram<<<NBLK, 512, 0, stream>>>(fkn, fqn, pneg, ppos);
    k_loss1<<<32, 256, 0, stream>>>(pneg, ppos, bsum);
    k_loss2<<<1, 64, 0, stream>>>(bsum, (float*)d_out);
}